// Round 1
// baseline (2264.932 us; speedup 1.0000x reference)
//
#include <hip/hip_runtime.h>
#include <math.h>

// APPNP: h = relu(x@W1+b1)@W2+b2 ; z_{k+1} = 0.9*Ahat z_k + 0.1*h (10 steps); log_softmax
// Ahat = D^-1/2 (A + I) D^-1/2, deg from target counts (+1 self loop).

constexpr float ALPHA_ = 0.1f;
constexpr int KSTEPS = 10;

// ---------------- preprocessing ----------------

__global__ void k_init_deg(float* __restrict__ deg, int n) {
    int i = blockIdx.x * 256 + threadIdx.x;
    if (i < n) deg[i] = 1.0f;  // self loop
}

__global__ void k_edge_deg(const int* __restrict__ ei, float* __restrict__ deg, int E) {
    int e = blockIdx.x * 256 + threadIdx.x;
    if (e < E) atomicAdd(&deg[ei[e]], 1.0f);  // ei[0..E) = row = targets
}

__global__ void k_dinv(const float* __restrict__ deg, float* __restrict__ dinv, int n) {
    int i = blockIdx.x * 256 + threadIdx.x;
    if (i < n) dinv[i] = rsqrtf(deg[i]);   // deg >= 1 always
}

// block sums of counts (in-degree = deg-1) for prefix scan
__global__ void k_blocksum(const float* __restrict__ deg, int* __restrict__ bsum, int n) {
    __shared__ int lds[4];
    int i = blockIdx.x * 256 + threadIdx.x;
    int c = (i < n) ? (int)deg[i] - 1 : 0;
    for (int o = 32; o; o >>= 1) c += __shfl_xor(c, o, 64);
    int w = threadIdx.x >> 6, lane = threadIdx.x & 63;
    if (lane == 0) lds[w] = c;
    __syncthreads();
    if (threadIdx.x == 0) bsum[blockIdx.x] = lds[0] + lds[1] + lds[2] + lds[3];
}

// exclusive scan of block sums (single block, nb <= 512)
__global__ void k_scan_bsum(const int* __restrict__ bsum, int* __restrict__ boff, int nb) {
    __shared__ int lds[512];
    int t = threadIdx.x;
    int orig = (t < nb) ? bsum[t] : 0;
    int v = orig;
    lds[t] = v;
    __syncthreads();
    for (int o = 1; o < 512; o <<= 1) {
        int add = (t >= o) ? lds[t - o] : 0;
        __syncthreads();
        v += add;
        lds[t] = v;
        __syncthreads();
    }
    if (t < nb) boff[t] = v - orig;
}

// per-block local exclusive scan + offset -> row_ptr, cursor
__global__ void k_scan_write(const float* __restrict__ deg, const int* __restrict__ boff,
                             int* __restrict__ row_ptr, int* __restrict__ cursor, int n) {
    __shared__ int lds[256];
    int i = blockIdx.x * 256 + threadIdx.x;
    int t = threadIdx.x;
    int c = (i < n) ? (int)deg[i] - 1 : 0;
    int v = c;
    lds[t] = v;
    __syncthreads();
    for (int o = 1; o < 256; o <<= 1) {
        int add = (t >= o) ? lds[t - o] : 0;
        __syncthreads();
        v += add;
        lds[t] = v;
        __syncthreads();
    }
    int excl = v - c + boff[blockIdx.x];
    if (i < n) {
        row_ptr[i] = excl;
        cursor[i] = excl;
        if (i == n - 1) row_ptr[n] = excl + c;
    }
}

__global__ void k_scatter(const int* __restrict__ ei, const float* __restrict__ dinv,
                          int* __restrict__ cursor, int* __restrict__ cols,
                          float* __restrict__ norms, int E) {
    int e = blockIdx.x * 256 + threadIdx.x;
    if (e >= E) return;
    int r = ei[e];
    int c = ei[E + e];
    int pos = atomicAdd(&cursor[r], 1);
    cols[pos] = c;
    norms[pos] = 0.9f * dinv[r] * dinv[c];  // (1-alpha) folded in
}

// ---------------- fused 2-layer MLP ----------------
// BM=128 rows/block, N=64, BK=64. 256 threads, each owns 8 rows x 4 cols.
// xsT: [64 k][128 row] stride 132 (pad 4 -> float4-aligned rows, 2-way-max conflicts)
// ws : [64 k][64 col]  stride 68
__launch_bounds__(256)
__global__ void k_gemm_fused(const float* __restrict__ x, const float* __restrict__ w1,
                             const float* __restrict__ b1, const float* __restrict__ w2,
                             const float* __restrict__ b2, float* __restrict__ h,
                             int M, int F) {
    __shared__ __align__(16) float xsT[64 * 132];
    __shared__ __align__(16) float ws[64 * 68];
    int tid = threadIdx.x;
    int cg = tid & 15, rg = tid >> 4;
    int c0 = cg * 4, r0 = rg * 8;
    int m0 = blockIdx.x * 128;

    float acc[8][4];
#pragma unroll
    for (int i = 0; i < 8; ++i)
#pragma unroll
        for (int j = 0; j < 4; ++j) acc[i][j] = 0.f;

    for (int kc = 0; kc < F; kc += 64) {
        // stage x chunk (transposed) : 128 rows x 64 k = 2048 float4 loads
#pragma unroll
        for (int it = 0; it < 8; ++it) {
            int idx = it * 256 + tid;
            int row = idx >> 4;
            int k0 = (idx & 15) * 4;
            int gr = m0 + row;
            float4 v = make_float4(0.f, 0.f, 0.f, 0.f);
            if (gr < M) v = *reinterpret_cast<const float4*>(&x[(size_t)gr * F + kc + k0]);
            xsT[(k0 + 0) * 132 + row] = v.x;
            xsT[(k0 + 1) * 132 + row] = v.y;
            xsT[(k0 + 2) * 132 + row] = v.z;
            xsT[(k0 + 3) * 132 + row] = v.w;
        }
        // stage w1 chunk 64x64
#pragma unroll
        for (int it = 0; it < 16; ++it) {
            int idx = it * 256 + tid;
            int kk = idx >> 6, cc = idx & 63;
            ws[kk * 68 + cc] = w1[(size_t)(kc + kk) * 64 + cc];
        }
        __syncthreads();
#pragma unroll
        for (int kk = 0; kk < 64; ++kk) {
            float4 xa = *reinterpret_cast<const float4*>(&xsT[kk * 132 + r0]);
            float4 xb = *reinterpret_cast<const float4*>(&xsT[kk * 132 + r0 + 4]);
            float4 wv = *reinterpret_cast<const float4*>(&ws[kk * 68 + c0]);
            float xr[8] = {xa.x, xa.y, xa.z, xa.w, xb.x, xb.y, xb.z, xb.w};
            float wr[4] = {wv.x, wv.y, wv.z, wv.w};
#pragma unroll
            for (int i = 0; i < 8; ++i)
#pragma unroll
                for (int j = 0; j < 4; ++j) acc[i][j] = fmaf(xr[i], wr[j], acc[i][j]);
        }
        __syncthreads();
    }

    // epilogue: relu(acc + b1) -> LDS (as h1T), then x W2 + b2
    float bb[4] = {b1[c0], b1[c0 + 1], b1[c0 + 2], b1[c0 + 3]};
#pragma unroll
    for (int i = 0; i < 8; ++i)
#pragma unroll
        for (int j = 0; j < 4; ++j)
            xsT[(c0 + j) * 132 + (r0 + i)] = fmaxf(acc[i][j] + bb[j], 0.f);
#pragma unroll
    for (int it = 0; it < 16; ++it) {
        int idx = it * 256 + tid;
        int kk = idx >> 6, cc = idx & 63;
        ws[kk * 68 + cc] = w2[(size_t)kk * 64 + cc];
    }
    __syncthreads();

    float acc2[8][4];
#pragma unroll
    for (int i = 0; i < 8; ++i)
#pragma unroll
        for (int j = 0; j < 4; ++j) acc2[i][j] = 0.f;
#pragma unroll
    for (int kk = 0; kk < 64; ++kk) {
        float4 xa = *reinterpret_cast<const float4*>(&xsT[kk * 132 + r0]);
        float4 xb = *reinterpret_cast<const float4*>(&xsT[kk * 132 + r0 + 4]);
        float4 wv = *reinterpret_cast<const float4*>(&ws[kk * 68 + c0]);
        float xr[8] = {xa.x, xa.y, xa.z, xa.w, xb.x, xb.y, xb.z, xb.w};
        float wr[4] = {wv.x, wv.y, wv.z, wv.w};
#pragma unroll
        for (int i = 0; i < 8; ++i)
#pragma unroll
            for (int j = 0; j < 4; ++j) acc2[i][j] = fmaf(xr[i], wr[j], acc2[i][j]);
    }
    float b2v[4] = {b2[c0], b2[c0 + 1], b2[c0 + 2], b2[c0 + 3]};
#pragma unroll
    for (int i = 0; i < 8; ++i) {
        int gr = m0 + r0 + i;
        if (gr < M) {
            float4 o = make_float4(acc2[i][0] + b2v[0], acc2[i][1] + b2v[1],
                                   acc2[i][2] + b2v[2], acc2[i][3] + b2v[3]);
            *reinterpret_cast<float4*>(&h[(size_t)gr * 64 + c0]) = o;
        }
    }
}

// ---------------- propagation (pull over CSR) ----------------
// one wave per node; lane = feature
__global__ void k_prop(const float* __restrict__ zin, const float* __restrict__ h,
                       const float* __restrict__ dinv, const int* __restrict__ row_ptr,
                       const int* __restrict__ cols, const float* __restrict__ norms,
                       float* __restrict__ zout, int n) {
    int wid = threadIdx.x >> 6;
    int lane = threadIdx.x & 63;
    int i = blockIdx.x * 4 + wid;
    if (i >= n) return;
    float di = dinv[i];
    size_t i64 = (size_t)i * 64;
    float acc = ALPHA_ * h[i64 + lane] + (1.f - ALPHA_) * di * di * zin[i64 + lane];
    int e = row_ptr[i], end = row_ptr[i + 1];
    for (; e + 4 <= end; e += 4) {
        int cc0 = cols[e], cc1 = cols[e + 1], cc2 = cols[e + 2], cc3 = cols[e + 3];
        float w0 = norms[e], w1 = norms[e + 1], w2 = norms[e + 2], w3 = norms[e + 3];
        float z0 = zin[(size_t)cc0 * 64 + lane];
        float z1 = zin[(size_t)cc1 * 64 + lane];
        float z2 = zin[(size_t)cc2 * 64 + lane];
        float z3 = zin[(size_t)cc3 * 64 + lane];
        acc = fmaf(w0, z0, acc);
        acc = fmaf(w1, z1, acc);
        acc = fmaf(w2, z2, acc);
        acc = fmaf(w3, z3, acc);
    }
    for (; e < end; ++e) acc = fmaf(norms[e], zin[(size_t)cols[e] * 64 + lane], acc);
    zout[i64 + lane] = acc;
}

__global__ void k_logsoftmax(const float* __restrict__ z, float* __restrict__ out, int n) {
    int wid = threadIdx.x >> 6;
    int lane = threadIdx.x & 63;
    int i = blockIdx.x * 4 + wid;
    if (i >= n) return;
    float v = z[(size_t)i * 64 + lane];
    float m = v;
    for (int o = 32; o; o >>= 1) m = fmaxf(m, __shfl_xor(m, o, 64));
    float p = expf(v - m);
    float s = p;
    for (int o = 32; o; o >>= 1) s += __shfl_xor(s, o, 64);
    out[(size_t)i * 64 + lane] = (v - m) - logf(s);
}

// ---------------- launch ----------------
extern "C" void kernel_launch(void* const* d_in, const int* in_sizes, int n_in,
                              void* d_out, int out_size, void* d_ws, size_t ws_size,
                              hipStream_t stream) {
    const float* x  = (const float*)d_in[0];
    const float* w1 = (const float*)d_in[1];
    const float* b1 = (const float*)d_in[2];
    const float* w2 = (const float*)d_in[3];
    const float* b2 = (const float*)d_in[4];
    const int*   ei = (const int*)d_in[5];
    // d_in[6] = K (always 10; launch count must be graph-static)

    int F = in_sizes[1] / 64;         // 1024
    int N = in_sizes[0] / F;          // 100000
    int E = in_sizes[5] / 2;          // 3200000

    char* p = (char*)d_ws;
    auto alloc = [&](size_t bytes) {
        void* r = (void*)p;
        p += (bytes + 255) & ~(size_t)255;
        return r;
    };
    float* h       = (float*)alloc((size_t)N * 64 * 4);
    float* zA      = (float*)alloc((size_t)N * 64 * 4);
    float* zB      = (float*)alloc((size_t)N * 64 * 4);
    float* deg     = (float*)alloc((size_t)N * 4);
    float* dinv    = (float*)alloc((size_t)N * 4);
    int*   row_ptr = (int*)alloc((size_t)(N + 1) * 4);
    int*   cursor  = (int*)alloc((size_t)N * 4);
    int*   bsum    = (int*)alloc(4096);
    int*   boff    = (int*)alloc(4096);
    int*   cols    = (int*)alloc((size_t)E * 4);
    float* norms   = (float*)alloc((size_t)E * 4);

    int nb  = (N + 255) / 256;
    int neb = (E + 255) / 256;

    k_init_deg<<<nb, 256, 0, stream>>>(deg, N);
    k_edge_deg<<<neb, 256, 0, stream>>>(ei, deg, E);
    k_dinv<<<nb, 256, 0, stream>>>(deg, dinv, N);
    k_blocksum<<<nb, 256, 0, stream>>>(deg, bsum, N);
    k_scan_bsum<<<1, 512, 0, stream>>>(bsum, boff, nb);
    k_scan_write<<<nb, 256, 0, stream>>>(deg, boff, row_ptr, cursor, N);
    k_scatter<<<neb, 256, 0, stream>>>(ei, dinv, cursor, cols, norms, E);
    k_gemm_fused<<<(N + 127) / 128, 256, 0, stream>>>(x, w1, b1, w2, b2, h, N, F);

    const float* zin = h;
    float* bufs[2] = {zA, zB};
    for (int k = 0; k < KSTEPS; ++k) {
        float* zo = bufs[k & 1];
        k_prop<<<(N + 3) / 4, 256, 0, stream>>>(zin, h, dinv, row_ptr, cols, norms, zo, N);
        zin = zo;
    }
    k_logsoftmax<<<(N + 3) / 4, 256, 0, stream>>>(zin, (float*)d_out, N);
}

// Round 2
// 1764.643 us; speedup vs baseline: 1.2835x; 1.2835x over previous
//
#include <hip/hip_runtime.h>
#include <math.h>

// APPNP: h = relu(x@W1+b1)@W2+b2 ; z_{k+1} = 0.9*Ahat z_k + 0.1*h (10 steps); log_softmax
// Ahat = D^-1/2 (A + I) D^-1/2, deg from target counts (+1 self loop).

constexpr float ALPHA_ = 0.1f;
constexpr int KSTEPS = 10;

typedef __attribute__((ext_vector_type(8))) short short8;
typedef __attribute__((ext_vector_type(4))) float f32x4;

static __device__ __forceinline__ short f2bf(float f) {
    unsigned u = __builtin_bit_cast(unsigned, f);
    unsigned r = (u + 0x7FFFu + ((u >> 16) & 1u)) >> 16;
    return (short)r;
}

// ---------------- preprocessing ----------------

__global__ void k_init_deg(float* __restrict__ deg, int n) {
    int i = blockIdx.x * 256 + threadIdx.x;
    if (i < n) deg[i] = 1.0f;  // self loop
}

__global__ void k_edge_deg(const int* __restrict__ ei, float* __restrict__ deg, int E) {
    int e = blockIdx.x * 256 + threadIdx.x;
    if (e < E) atomicAdd(&deg[ei[e]], 1.0f);  // ei[0..E) = row = targets
}

__global__ void k_dinv(const float* __restrict__ deg, float* __restrict__ dinv, int n) {
    int i = blockIdx.x * 256 + threadIdx.x;
    if (i < n) dinv[i] = rsqrtf(deg[i]);   // deg >= 1 always
}

// block sums of counts (in-degree = deg-1) for prefix scan
__global__ void k_blocksum(const float* __restrict__ deg, int* __restrict__ bsum, int n) {
    __shared__ int lds[4];
    int i = blockIdx.x * 256 + threadIdx.x;
    int c = (i < n) ? (int)deg[i] - 1 : 0;
    for (int o = 32; o; o >>= 1) c += __shfl_xor(c, o, 64);
    int w = threadIdx.x >> 6, lane = threadIdx.x & 63;
    if (lane == 0) lds[w] = c;
    __syncthreads();
    if (threadIdx.x == 0) bsum[blockIdx.x] = lds[0] + lds[1] + lds[2] + lds[3];
}

// exclusive scan of block sums (single block, nb <= 512)
__global__ void k_scan_bsum(const int* __restrict__ bsum, int* __restrict__ boff, int nb) {
    __shared__ int lds[512];
    int t = threadIdx.x;
    int orig = (t < nb) ? bsum[t] : 0;
    int v = orig;
    lds[t] = v;
    __syncthreads();
    for (int o = 1; o < 512; o <<= 1) {
        int add = (t >= o) ? lds[t - o] : 0;
        __syncthreads();
        v += add;
        lds[t] = v;
        __syncthreads();
    }
    if (t < nb) boff[t] = v - orig;
}

// per-block local exclusive scan + offset -> row_ptr, cursor
__global__ void k_scan_write(const float* __restrict__ deg, const int* __restrict__ boff,
                             int* __restrict__ row_ptr, int* __restrict__ cursor, int n) {
    __shared__ int lds[256];
    int i = blockIdx.x * 256 + threadIdx.x;
    int t = threadIdx.x;
    int c = (i < n) ? (int)deg[i] - 1 : 0;
    int v = c;
    lds[t] = v;
    __syncthreads();
    for (int o = 1; o < 256; o <<= 1) {
        int add = (t >= o) ? lds[t - o] : 0;
        __syncthreads();
        v += add;
        lds[t] = v;
        __syncthreads();
    }
    int excl = v - c + boff[blockIdx.x];
    if (i < n) {
        row_ptr[i] = excl;
        cursor[i] = excl;
        if (i == n - 1) row_ptr[n] = excl + c;
    }
}

__global__ void k_scatter(const int* __restrict__ ei, const float* __restrict__ dinv,
                          int* __restrict__ cursor, int* __restrict__ cols,
                          float* __restrict__ norms, int E) {
    int e = blockIdx.x * 256 + threadIdx.x;
    if (e >= E) return;
    int r = ei[e];
    int c = ei[E + e];
    int pos = atomicAdd(&cursor[r], 1);
    cols[pos] = c;
    norms[pos] = 0.9f * dinv[r] * dinv[c];  // (1-alpha) folded in
}

// ---------------- weight packing into MFMA fragment order ----------------
// w1f[kb(32)][nb(4)][lane(64)][8 bf16] = w1[kb*32 + (lane>>4)*8 + j][nb*16 + (lane&15)]
__global__ void k_pack_w1(const float* __restrict__ w1, short* __restrict__ w1f) {
    int t = blockIdx.x * 256 + threadIdx.x;  // 65536 total
    int j = t & 7, lane = (t >> 3) & 63, nb = (t >> 9) & 3, kb = t >> 11;
    int k = kb * 32 + ((lane >> 4) << 3) + j;
    int c = nb * 16 + (lane & 15);
    w1f[t] = f2bf(w1[k * 64 + c]);
}

__global__ void k_pack_w2(const float* __restrict__ w2, short* __restrict__ w2f) {
    int t = blockIdx.x * 256 + threadIdx.x;  // 4096 total
    int j = t & 7, lane = (t >> 3) & 63, nb = (t >> 9) & 3, kb = (t >> 11) & 1;
    int k = kb * 32 + ((lane >> 4) << 3) + j;
    int c = nb * 16 + (lane & 15);
    w2f[t] = f2bf(w2[k * 64 + c]);
}

// ---------------- fused 2-layer MLP via MFMA ----------------
// 256 threads = 4 waves; each wave owns 16 rows. A-frags straight from global x
// (f32->bf16 in reg). B-frags from pre-packed w1f/w2f (L2-resident).
__launch_bounds__(256)
__global__ void k_mlp(const float* __restrict__ x, const short8* __restrict__ w1f,
                      const float* __restrict__ b1, const short8* __restrict__ w2f,
                      const float* __restrict__ b2, float* __restrict__ h,
                      int M, int F) {
    __shared__ __align__(16) short c1s[4][16][64];  // per-wave 16x64 bf16 transpose buf
    int tid = threadIdx.x;
    int w = tid >> 6, lane = tid & 63;
    int hi = lane >> 4, lx = lane & 15;
    int rbase = blockIdx.x * 64 + w * 16;
    int row = rbase + lx;
    size_t rowc = (row < M) ? (size_t)row : (size_t)(M - 1);
    const float* xr = x + rowc * (size_t)F + hi * 8;

    f32x4 acc[4];
#pragma unroll
    for (int nb = 0; nb < 4; ++nb) acc[nb] = (f32x4){0.f, 0.f, 0.f, 0.f};

    int KK = F >> 5;  // 32 K-steps of 32
#pragma unroll 2
    for (int kk = 0; kk < KK; ++kk) {
        float4 a0 = *reinterpret_cast<const float4*>(xr + kk * 32);
        float4 a1 = *reinterpret_cast<const float4*>(xr + kk * 32 + 4);
        short8 af;
        af[0] = f2bf(a0.x); af[1] = f2bf(a0.y); af[2] = f2bf(a0.z); af[3] = f2bf(a0.w);
        af[4] = f2bf(a1.x); af[5] = f2bf(a1.y); af[6] = f2bf(a1.z); af[7] = f2bf(a1.w);
#pragma unroll
        for (int nb = 0; nb < 4; ++nb) {
            short8 bf = w1f[(kk * 4 + nb) * 64 + lane];
            acc[nb] = __builtin_amdgcn_mfma_f32_16x16x32_bf16(af, bf, acc[nb], 0, 0, 0);
        }
    }

    // bias + relu -> LDS (C/D layout: row=(lane>>4)*4+r, col=nb*16+(lane&15))
    short* my = &c1s[w][0][0];
#pragma unroll
    for (int nb = 0; nb < 4; ++nb) {
        int col = nb * 16 + lx;
        float bb = b1[col];
#pragma unroll
        for (int r = 0; r < 4; ++r) {
            int rr = hi * 4 + r;
            my[rr * 64 + col] = f2bf(fmaxf(acc[nb][r] + bb, 0.f));
        }
    }
    __syncthreads();

    // layer 2: A2 row = lx, k = kb*32 + hi*8 + j  (16B contiguous LDS read)
    f32x4 acc2[4];
#pragma unroll
    for (int nb = 0; nb < 4; ++nb) acc2[nb] = (f32x4){0.f, 0.f, 0.f, 0.f};
#pragma unroll
    for (int kb = 0; kb < 2; ++kb) {
        short8 af2 = *reinterpret_cast<const short8*>(&my[lx * 64 + kb * 32 + hi * 8]);
#pragma unroll
        for (int nb = 0; nb < 4; ++nb) {
            short8 bf2 = w2f[(kb * 4 + nb) * 64 + lane];
            acc2[nb] = __builtin_amdgcn_mfma_f32_16x16x32_bf16(af2, bf2, acc2[nb], 0, 0, 0);
        }
    }

#pragma unroll
    for (int nb = 0; nb < 4; ++nb) {
        int col = nb * 16 + lx;
        float bb = b2[col];
#pragma unroll
        for (int r = 0; r < 4; ++r) {
            int orow = rbase + hi * 4 + r;
            if (orow < M) h[(size_t)orow * 64 + col] = acc2[nb][r] + bb;
        }
    }
}

// ---------------- propagation (pull over CSR) ----------------
// one wave per node; lane = feature
__global__ void k_prop(const float* __restrict__ zin, const float* __restrict__ h,
                       const float* __restrict__ dinv, const int* __restrict__ row_ptr,
                       const int* __restrict__ cols, const float* __restrict__ norms,
                       float* __restrict__ zout, int n) {
    int wid = threadIdx.x >> 6;
    int lane = threadIdx.x & 63;
    int i = blockIdx.x * 4 + wid;
    if (i >= n) return;
    float di = dinv[i];
    size_t i64 = (size_t)i * 64;
    float acc = ALPHA_ * h[i64 + lane] + (1.f - ALPHA_) * di * di * zin[i64 + lane];
    int e = row_ptr[i], end = row_ptr[i + 1];
    for (; e + 4 <= end; e += 4) {
        int cc0 = cols[e], cc1 = cols[e + 1], cc2 = cols[e + 2], cc3 = cols[e + 3];
        float w0 = norms[e], w1 = norms[e + 1], w2 = norms[e + 2], w3 = norms[e + 3];
        float z0 = zin[(size_t)cc0 * 64 + lane];
        float z1 = zin[(size_t)cc1 * 64 + lane];
        float z2 = zin[(size_t)cc2 * 64 + lane];
        float z3 = zin[(size_t)cc3 * 64 + lane];
        acc = fmaf(w0, z0, acc);
        acc = fmaf(w1, z1, acc);
        acc = fmaf(w2, z2, acc);
        acc = fmaf(w3, z3, acc);
    }
    for (; e < end; ++e) acc = fmaf(norms[e], zin[(size_t)cols[e] * 64 + lane], acc);
    zout[i64 + lane] = acc;
}

__global__ void k_logsoftmax(const float* __restrict__ z, float* __restrict__ out, int n) {
    int wid = threadIdx.x >> 6;
    int lane = threadIdx.x & 63;
    int i = blockIdx.x * 4 + wid;
    if (i >= n) return;
    float v = z[(size_t)i * 64 + lane];
    float m = v;
    for (int o = 32; o; o >>= 1) m = fmaxf(m, __shfl_xor(m, o, 64));
    float p = expf(v - m);
    float s = p;
    for (int o = 32; o; o >>= 1) s += __shfl_xor(s, o, 64);
    out[(size_t)i * 64 + lane] = (v - m) - logf(s);
}

// ---------------- launch ----------------
extern "C" void kernel_launch(void* const* d_in, const int* in_sizes, int n_in,
                              void* d_out, int out_size, void* d_ws, size_t ws_size,
                              hipStream_t stream) {
    const float* x  = (const float*)d_in[0];
    const float* w1 = (const float*)d_in[1];
    const float* b1 = (const float*)d_in[2];
    const float* w2 = (const float*)d_in[3];
    const float* b2 = (const float*)d_in[4];
    const int*   ei = (const int*)d_in[5];
    // d_in[6] = K (always 10; launch count must be graph-static)

    int F = in_sizes[1] / 64;         // 1024
    int N = in_sizes[0] / F;          // 100000
    int E = in_sizes[5] / 2;          // 3200000

    char* p = (char*)d_ws;
    auto alloc = [&](size_t bytes) {
        void* r = (void*)p;
        p += (bytes + 255) & ~(size_t)255;
        return r;
    };
    float* h       = (float*)alloc((size_t)N * 64 * 4);
    float* zA      = (float*)alloc((size_t)N * 64 * 4);
    float* zB      = (float*)alloc((size_t)N * 64 * 4);
    float* deg     = (float*)alloc((size_t)N * 4);
    float* dinv    = (float*)alloc((size_t)N * 4);
    int*   row_ptr = (int*)alloc((size_t)(N + 1) * 4);
    int*   cursor  = (int*)alloc((size_t)N * 4);
    int*   bsum    = (int*)alloc(4096);
    int*   boff    = (int*)alloc(4096);
    int*   cols    = (int*)alloc((size_t)E * 4);
    float* norms   = (float*)alloc((size_t)E * 4);
    short* w1f     = (short*)alloc((size_t)F * 64 * 2);
    short* w2f     = (short*)alloc((size_t)64 * 64 * 2);

    int nb  = (N + 255) / 256;
    int neb = (E + 255) / 256;

    k_init_deg<<<nb, 256, 0, stream>>>(deg, N);
    k_edge_deg<<<neb, 256, 0, stream>>>(ei, deg, E);
    k_dinv<<<nb, 256, 0, stream>>>(deg, dinv, N);
    k_blocksum<<<nb, 256, 0, stream>>>(deg, bsum, N);
    k_scan_bsum<<<1, 512, 0, stream>>>(bsum, boff, nb);
    k_scan_write<<<nb, 256, 0, stream>>>(deg, boff, row_ptr, cursor, N);
    k_scatter<<<neb, 256, 0, stream>>>(ei, dinv, cursor, cols, norms, E);
    k_pack_w1<<<(F * 64) / 256, 256, 0, stream>>>(w1, w1f);
    k_pack_w2<<<16, 256, 0, stream>>>(w2, w2f);
    k_mlp<<<(N + 63) / 64, 256, 0, stream>>>(x, (const short8*)w1f, b1,
                                             (const short8*)w2f, b2, h, N, F);

    const float* zin = h;
    float* bufs[2] = {zA, zB};
    for (int k = 0; k < KSTEPS; ++k) {
        float* zo = bufs[k & 1];
        k_prop<<<(N + 3) / 4, 256, 0, stream>>>(zin, h, dinv, row_ptr, cols, norms, zo, N);
        zin = zo;
    }
    k_logsoftmax<<<(N + 3) / 4, 256, 0, stream>>>(zin, (float*)d_out, N);
}

// Round 3
// 1531.441 us; speedup vs baseline: 1.4790x; 1.1523x over previous
//
#include <hip/hip_runtime.h>
#include <math.h>

// APPNP: h = relu(x@W1+b1)@W2+b2 ; z_{k+1} = 0.9*Ahat z_k + 0.1*h (10 steps); log_softmax
// Ahat = D^-1/2 (A + I) D^-1/2. Propagation state z kept in bf16 (gather-BW bound),
// accumulation in f32, teleport term from f32 h.

constexpr float ALPHA_ = 0.1f;
constexpr int KSTEPS = 10;

typedef __attribute__((ext_vector_type(8))) short short8;
typedef __attribute__((ext_vector_type(4))) float f32x4;

static __device__ __forceinline__ short f2bf(float f) {
    unsigned u = __builtin_bit_cast(unsigned, f);
    unsigned r = (u + 0x7FFFu + ((u >> 16) & 1u)) >> 16;
    return (short)r;
}
static __device__ __forceinline__ float bf2f(unsigned short b) {
    unsigned u = (unsigned)b << 16;
    return __builtin_bit_cast(float, u);
}

// ---------------- preprocessing ----------------

__global__ void k_init_deg(float* __restrict__ deg, int n) {
    int i = blockIdx.x * 256 + threadIdx.x;
    if (i < n) deg[i] = 1.0f;  // self loop
}

__global__ void k_edge_deg(const int* __restrict__ ei, float* __restrict__ deg, int E) {
    int e = blockIdx.x * 256 + threadIdx.x;
    if (e < E) atomicAdd(&deg[ei[e]], 1.0f);  // ei[0..E) = row = targets
}

__global__ void k_dinv(const float* __restrict__ deg, float* __restrict__ dinv, int n) {
    int i = blockIdx.x * 256 + threadIdx.x;
    if (i < n) dinv[i] = rsqrtf(deg[i]);   // deg >= 1 always
}

// block sums of counts (in-degree = deg-1) for prefix scan
__global__ void k_blocksum(const float* __restrict__ deg, int* __restrict__ bsum, int n) {
    __shared__ int lds[4];
    int i = blockIdx.x * 256 + threadIdx.x;
    int c = (i < n) ? (int)deg[i] - 1 : 0;
    for (int o = 32; o; o >>= 1) c += __shfl_xor(c, o, 64);
    int w = threadIdx.x >> 6, lane = threadIdx.x & 63;
    if (lane == 0) lds[w] = c;
    __syncthreads();
    if (threadIdx.x == 0) bsum[blockIdx.x] = lds[0] + lds[1] + lds[2] + lds[3];
}

// exclusive scan of block sums (single block, nb <= 512)
__global__ void k_scan_bsum(const int* __restrict__ bsum, int* __restrict__ boff, int nb) {
    __shared__ int lds[512];
    int t = threadIdx.x;
    int orig = (t < nb) ? bsum[t] : 0;
    int v = orig;
    lds[t] = v;
    __syncthreads();
    for (int o = 1; o < 512; o <<= 1) {
        int add = (t >= o) ? lds[t - o] : 0;
        __syncthreads();
        v += add;
        lds[t] = v;
        __syncthreads();
    }
    if (t < nb) boff[t] = v - orig;
}

// per-block local exclusive scan + offset -> row_ptr, cursor
__global__ void k_scan_write(const float* __restrict__ deg, const int* __restrict__ boff,
                             int* __restrict__ row_ptr, int* __restrict__ cursor, int n) {
    __shared__ int lds[256];
    int i = blockIdx.x * 256 + threadIdx.x;
    int t = threadIdx.x;
    int c = (i < n) ? (int)deg[i] - 1 : 0;
    int v = c;
    lds[t] = v;
    __syncthreads();
    for (int o = 1; o < 256; o <<= 1) {
        int add = (t >= o) ? lds[t - o] : 0;
        __syncthreads();
        v += add;
        lds[t] = v;
        __syncthreads();
    }
    int excl = v - c + boff[blockIdx.x];
    if (i < n) {
        row_ptr[i] = excl;
        cursor[i] = excl;
        if (i == n - 1) row_ptr[n] = excl + c;
    }
}

// paired (col, norm) scatter: single 8B store per edge (halves line traffic)
__global__ void k_scatter(const int* __restrict__ ei, const float* __restrict__ dinv,
                          int* __restrict__ cursor, int2* __restrict__ en, int E) {
    int e = blockIdx.x * 256 + threadIdx.x;
    if (e >= E) return;
    int r = ei[e];
    int c = ei[E + e];
    int pos = atomicAdd(&cursor[r], 1);
    float nrm = 0.9f * dinv[r] * dinv[c];  // (1-alpha) folded in
    en[pos] = make_int2(c, __builtin_bit_cast(int, nrm));
}

// ---------------- weight packing into MFMA fragment order ----------------
__global__ void k_pack_w1(const float* __restrict__ w1, short* __restrict__ w1f) {
    int t = blockIdx.x * 256 + threadIdx.x;  // 65536 total
    int j = t & 7, lane = (t >> 3) & 63, nb = (t >> 9) & 3, kb = t >> 11;
    int k = kb * 32 + ((lane >> 4) << 3) + j;
    int c = nb * 16 + (lane & 15);
    w1f[t] = f2bf(w1[k * 64 + c]);
}

__global__ void k_pack_w2(const float* __restrict__ w2, short* __restrict__ w2f) {
    int t = blockIdx.x * 256 + threadIdx.x;  // 4096 total
    int j = t & 7, lane = (t >> 3) & 63, nb = (t >> 9) & 3, kb = (t >> 11) & 1;
    int k = kb * 32 + ((lane >> 4) << 3) + j;
    int c = nb * 16 + (lane & 15);
    w2f[t] = f2bf(w2[k * 64 + c]);
}

// ---------------- fused 2-layer MLP via MFMA ----------------
__launch_bounds__(256)
__global__ void k_mlp(const float* __restrict__ x, const short8* __restrict__ w1f,
                      const float* __restrict__ b1, const short8* __restrict__ w2f,
                      const float* __restrict__ b2, float* __restrict__ h,
                      unsigned short* __restrict__ hbf, int M, int F) {
    __shared__ __align__(16) short c1s[4][16][64];
    int tid = threadIdx.x;
    int w = tid >> 6, lane = tid & 63;
    int hi = lane >> 4, lx = lane & 15;
    int rbase = blockIdx.x * 64 + w * 16;
    int row = rbase + lx;
    size_t rowc = (row < M) ? (size_t)row : (size_t)(M - 1);
    const float* xr = x + rowc * (size_t)F + hi * 8;

    f32x4 acc[4];
#pragma unroll
    for (int nb = 0; nb < 4; ++nb) acc[nb] = (f32x4){0.f, 0.f, 0.f, 0.f};

    int KK = F >> 5;
#pragma unroll 2
    for (int kk = 0; kk < KK; ++kk) {
        float4 a0 = *reinterpret_cast<const float4*>(xr + kk * 32);
        float4 a1 = *reinterpret_cast<const float4*>(xr + kk * 32 + 4);
        short8 af;
        af[0] = f2bf(a0.x); af[1] = f2bf(a0.y); af[2] = f2bf(a0.z); af[3] = f2bf(a0.w);
        af[4] = f2bf(a1.x); af[5] = f2bf(a1.y); af[6] = f2bf(a1.z); af[7] = f2bf(a1.w);
#pragma unroll
        for (int nb = 0; nb < 4; ++nb) {
            short8 bf = w1f[(kk * 4 + nb) * 64 + lane];
            acc[nb] = __builtin_amdgcn_mfma_f32_16x16x32_bf16(af, bf, acc[nb], 0, 0, 0);
        }
    }

    short* my = &c1s[w][0][0];
#pragma unroll
    for (int nb = 0; nb < 4; ++nb) {
        int col = nb * 16 + lx;
        float bb = b1[col];
#pragma unroll
        for (int r = 0; r < 4; ++r) {
            int rr = hi * 4 + r;
            my[rr * 64 + col] = f2bf(fmaxf(acc[nb][r] + bb, 0.f));
        }
    }
    __syncthreads();

    f32x4 acc2[4];
#pragma unroll
    for (int nb = 0; nb < 4; ++nb) acc2[nb] = (f32x4){0.f, 0.f, 0.f, 0.f};
#pragma unroll
    for (int kb = 0; kb < 2; ++kb) {
        short8 af2 = *reinterpret_cast<const short8*>(&my[lx * 64 + kb * 32 + hi * 8]);
#pragma unroll
        for (int nb = 0; nb < 4; ++nb) {
            short8 bf2 = w2f[(kb * 4 + nb) * 64 + lane];
            acc2[nb] = __builtin_amdgcn_mfma_f32_16x16x32_bf16(af2, bf2, acc2[nb], 0, 0, 0);
        }
    }

#pragma unroll
    for (int nb = 0; nb < 4; ++nb) {
        int col = nb * 16 + lx;
        float bb = b2[col];
#pragma unroll
        for (int r = 0; r < 4; ++r) {
            int orow = rbase + hi * 4 + r;
            if (orow < M) {
                float v = acc2[nb][r] + bb;
                h[(size_t)orow * 64 + col] = v;
                hbf[(size_t)orow * 64 + col] = (unsigned short)f2bf(v);
            }
        }
    }
}

// ---------------- propagation (pull over CSR, bf16 state) ----------------
__global__ void k_prop(const unsigned short* __restrict__ zin, const float* __restrict__ h,
                       const float* __restrict__ dinv, const int* __restrict__ row_ptr,
                       const int2* __restrict__ en, unsigned short* __restrict__ zout, int n) {
    int wid = threadIdx.x >> 6;
    int lane = threadIdx.x & 63;
    int i = blockIdx.x * 4 + wid;
    if (i >= n) return;
    float di = dinv[i];
    size_t i64 = (size_t)i * 64;
    float acc = ALPHA_ * h[i64 + lane] + 0.9f * di * di * bf2f(zin[i64 + lane]);
    int e = row_ptr[i], end = row_ptr[i + 1];
    for (; e + 4 <= end; e += 4) {
        int2 p0 = en[e], p1 = en[e + 1], p2 = en[e + 2], p3 = en[e + 3];
        float z0 = bf2f(zin[(size_t)p0.x * 64 + lane]);
        float z1 = bf2f(zin[(size_t)p1.x * 64 + lane]);
        float z2 = bf2f(zin[(size_t)p2.x * 64 + lane]);
        float z3 = bf2f(zin[(size_t)p3.x * 64 + lane]);
        acc = fmaf(__builtin_bit_cast(float, p0.y), z0, acc);
        acc = fmaf(__builtin_bit_cast(float, p1.y), z1, acc);
        acc = fmaf(__builtin_bit_cast(float, p2.y), z2, acc);
        acc = fmaf(__builtin_bit_cast(float, p3.y), z3, acc);
    }
    for (; e < end; ++e) {
        int2 p = en[e];
        acc = fmaf(__builtin_bit_cast(float, p.y), bf2f(zin[(size_t)p.x * 64 + lane]), acc);
    }
    zout[i64 + lane] = (unsigned short)f2bf(acc);
}

// final step fused with log_softmax, writes f32 out
__global__ void k_prop_lsm(const unsigned short* __restrict__ zin, const float* __restrict__ h,
                           const float* __restrict__ dinv, const int* __restrict__ row_ptr,
                           const int2* __restrict__ en, float* __restrict__ out, int n) {
    int wid = threadIdx.x >> 6;
    int lane = threadIdx.x & 63;
    int i = blockIdx.x * 4 + wid;
    if (i >= n) return;
    float di = dinv[i];
    size_t i64 = (size_t)i * 64;
    float acc = ALPHA_ * h[i64 + lane] + 0.9f * di * di * bf2f(zin[i64 + lane]);
    int e = row_ptr[i], end = row_ptr[i + 1];
    for (; e + 4 <= end; e += 4) {
        int2 p0 = en[e], p1 = en[e + 1], p2 = en[e + 2], p3 = en[e + 3];
        float z0 = bf2f(zin[(size_t)p0.x * 64 + lane]);
        float z1 = bf2f(zin[(size_t)p1.x * 64 + lane]);
        float z2 = bf2f(zin[(size_t)p2.x * 64 + lane]);
        float z3 = bf2f(zin[(size_t)p3.x * 64 + lane]);
        acc = fmaf(__builtin_bit_cast(float, p0.y), z0, acc);
        acc = fmaf(__builtin_bit_cast(float, p1.y), z1, acc);
        acc = fmaf(__builtin_bit_cast(float, p2.y), z2, acc);
        acc = fmaf(__builtin_bit_cast(float, p3.y), z3, acc);
    }
    for (; e < end; ++e) {
        int2 p = en[e];
        acc = fmaf(__builtin_bit_cast(float, p.y), bf2f(zin[(size_t)p.x * 64 + lane]), acc);
    }
    float m = acc;
    for (int o = 32; o; o >>= 1) m = fmaxf(m, __shfl_xor(m, o, 64));
    float pp = expf(acc - m);
    float s = pp;
    for (int o = 32; o; o >>= 1) s += __shfl_xor(s, o, 64);
    out[i64 + lane] = (acc - m) - logf(s);
}

// ---------------- launch ----------------
extern "C" void kernel_launch(void* const* d_in, const int* in_sizes, int n_in,
                              void* d_out, int out_size, void* d_ws, size_t ws_size,
                              hipStream_t stream) {
    const float* x  = (const float*)d_in[0];
    const float* w1 = (const float*)d_in[1];
    const float* b1 = (const float*)d_in[2];
    const float* w2 = (const float*)d_in[3];
    const float* b2 = (const float*)d_in[4];
    const int*   ei = (const int*)d_in[5];
    // d_in[6] = K (always 10; launch count must be graph-static)

    int F = in_sizes[1] / 64;         // 1024
    int N = in_sizes[0] / F;          // 100000
    int E = in_sizes[5] / 2;          // 3200000

    char* p = (char*)d_ws;
    auto alloc = [&](size_t bytes) {
        void* r = (void*)p;
        p += (bytes + 255) & ~(size_t)255;
        return r;
    };
    float*          h    = (float*)alloc((size_t)N * 64 * 4);
    unsigned short* hbf  = (unsigned short*)alloc((size_t)N * 64 * 2);
    unsigned short* zA   = (unsigned short*)alloc((size_t)N * 64 * 2);
    unsigned short* zB   = (unsigned short*)alloc((size_t)N * 64 * 2);
    float* deg     = (float*)alloc((size_t)N * 4);
    float* dinv    = (float*)alloc((size_t)N * 4);
    int*   row_ptr = (int*)alloc((size_t)(N + 1) * 4);
    int*   cursor  = (int*)alloc((size_t)N * 4);
    int*   bsum    = (int*)alloc(4096);
    int*   boff    = (int*)alloc(4096);
    int2*  en      = (int2*)alloc((size_t)E * 8);
    short* w1f     = (short*)alloc((size_t)F * 64 * 2);
    short* w2f     = (short*)alloc((size_t)64 * 64 * 2);

    int nb  = (N + 255) / 256;
    int neb = (E + 255) / 256;

    k_init_deg<<<nb, 256, 0, stream>>>(deg, N);
    k_edge_deg<<<neb, 256, 0, stream>>>(ei, deg, E);
    k_dinv<<<nb, 256, 0, stream>>>(deg, dinv, N);
    k_blocksum<<<nb, 256, 0, stream>>>(deg, bsum, N);
    k_scan_bsum<<<1, 512, 0, stream>>>(bsum, boff, nb);
    k_scan_write<<<nb, 256, 0, stream>>>(deg, boff, row_ptr, cursor, N);
    k_scatter<<<neb, 256, 0, stream>>>(ei, dinv, cursor, en, E);
    k_pack_w1<<<(F * 64) / 256, 256, 0, stream>>>(w1, w1f);
    k_pack_w2<<<16, 256, 0, stream>>>(w2, w2f);
    k_mlp<<<(N + 63) / 64, 256, 0, stream>>>(x, (const short8*)w1f, b1,
                                             (const short8*)w2f, b2, h, hbf, N, F);

    const unsigned short* zin = hbf;
    unsigned short* bufs[2] = {zA, zB};
    for (int k = 0; k < KSTEPS - 1; ++k) {
        unsigned short* zo = bufs[k & 1];
        k_prop<<<(N + 3) / 4, 256, 0, stream>>>(zin, h, dinv, row_ptr, en, zo, N);
        zin = zo;
    }
    k_prop_lsm<<<(N + 3) / 4, 256, 0, stream>>>(zin, h, dinv, row_ptr, en, (float*)d_out, N);
}